// Round 2
// baseline (432.669 us; speedup 1.0000x reference)
//
#include <hip/hip_runtime.h>

#define N_IMG 8
#define K_INS 16
#define CCH   64
#define EPSV  1e-5f

// workspace layout (bytes):
//   [0, 65536)          float2 stats[N][K][C]   (sum, sumsq)  -- fully written each call
//   [65536, 66048)      int    cnt[N][K]        -- zeroed via hipMemsetAsync each call
//   [66048, 131584)     float2 scsh[N][K][C]    (scale, shift) -- fully written each call
#define STATS_OFF 0
#define CNT_OFF   65536
#define SCSH_OFF  66048

__global__ __launch_bounds__(256) void count_kernel(const int* __restrict__ ids,
                                                    int* __restrict__ cnt, int HW) {
    // grid: (tilesPerImg=32, N). tile = HW/32 ids; each of 4 waves takes a quarter.
    const int n = blockIdx.y;
    const int tileSize = HW / 32;
    const int quarter = tileSize / 4;
    const int lane = threadIdx.x & 63;
    const int wave = threadIdx.x >> 6;
    const int wbase = blockIdx.x * tileSize + wave * quarter;
    const int* p = ids + (size_t)n * HW;

    int myc[K_INS];
#pragma unroll
    for (int k = 0; k < K_INS; ++k) myc[k] = 0;

    for (int i = wbase + lane; i < wbase + quarter; i += 64) {
        int id = p[i];
#pragma unroll
        for (int k = 0; k < K_INS; ++k) {
            unsigned long long m = __ballot(id == k);
            if (lane == 0) myc[k] += __popcll(m);
        }
    }
    if (lane == 0) {
#pragma unroll
        for (int k = 0; k < K_INS; ++k) atomicAdd(&cnt[n * K_INS + k], myc[k]);
    }
}

__global__ __launch_bounds__(256) void stats_kernel(const float* __restrict__ x,
                                                    const int* __restrict__ ids,
                                                    float2* __restrict__ stats, int HW) {
    // grid: (C, N). Block owns one (n,c): accumulates sum/sumsq for all K instances.
    const int c = blockIdx.x;
    const int n = blockIdx.y;
    const int t = threadIdx.x;

    // Per-thread-private LDS accumulator cells, updated with NON-RETURNING LDS
    // float atomics (ds_add_f32): no register dependency chain, LDS-pipe
    // throughput-bound instead of latency-bound. Each cell has exactly one
    // writer thread -> bitwise deterministic despite atomics.
    // Layout: acc[k*512 + t*2 + {0,1}] -> banks (t*2)%32 / (t*2+1)%32:
    // 2 lanes/bank per wave instruction = conflict-free.
    __shared__ float acc[K_INS * 256 * 2];
#pragma unroll
    for (int k = 0; k < K_INS; ++k) {
        acc[k * 512 + t * 2 + 0] = 0.f;
        acc[k * 512 + t * 2 + 1] = 0.f;
    }
    __syncthreads();

    const float4* x4 = (const float4*)(x + ((size_t)n * CCH + c) * HW);
    const int4* i4 = (const int4*)(ids + (size_t)n * HW);

    const int iters = HW / (256 * 4);
#pragma unroll 2
    for (int j = 0; j < iters; ++j) {
        int idx = j * 256 + t;
        float4 xv = x4[idx];
        int4 id = i4[idx];
        if (id.x >= 0) {
            atomicAdd(&acc[id.x * 512 + t * 2 + 0], xv.x);
            atomicAdd(&acc[id.x * 512 + t * 2 + 1], xv.x * xv.x);
        }
        if (id.y >= 0) {
            atomicAdd(&acc[id.y * 512 + t * 2 + 0], xv.y);
            atomicAdd(&acc[id.y * 512 + t * 2 + 1], xv.y * xv.y);
        }
        if (id.z >= 0) {
            atomicAdd(&acc[id.z * 512 + t * 2 + 0], xv.z);
            atomicAdd(&acc[id.z * 512 + t * 2 + 1], xv.z * xv.z);
        }
        if (id.w >= 0) {
            atomicAdd(&acc[id.w * 512 + t * 2 + 0], xv.w);
            atomicAdd(&acc[id.w * 512 + t * 2 + 1], xv.w * xv.w);
        }
    }
    __syncthreads();

    // reduce: wave w handles k in [w*4, w*4+4); sum 256 cells per k.
    const int wave = t >> 6, lane = t & 63;
#pragma unroll
    for (int kk = 0; kk < 4; ++kk) {
        int k = wave * 4 + kk;
        float s = 0.f, q = 0.f;
#pragma unroll
        for (int r = 0; r < 4; ++r) {
            s += acc[k * 512 + (lane + 64 * r) * 2 + 0];
            q += acc[k * 512 + (lane + 64 * r) * 2 + 1];
        }
#pragma unroll
        for (int off = 32; off > 0; off >>= 1) {
            s += __shfl_down(s, off);
            q += __shfl_down(q, off);
        }
        if (lane == 0) stats[((size_t)n * K_INS + k) * CCH + c] = make_float2(s, q);
    }
}

__global__ __launch_bounds__(256) void finalize_kernel(const float2* __restrict__ stats,
                                                       const int* __restrict__ cnt,
                                                       const float* __restrict__ gamma,
                                                       const float* __restrict__ beta,
                                                       float2* __restrict__ scsh) {
    int i = blockIdx.x * 256 + threadIdx.x;  // over N*K*C = 8192
    if (i >= N_IMG * K_INS * CCH) return;
    int c = i % CCH;
    int nk = i / CCH;
    float2 s = stats[i];
    float denom = fmaxf((float)cnt[nk], 1.0f);
    float mean = s.x / denom;
    float var = s.y / denom - mean * mean;
    float r = rsqrtf(var + EPSV);
    float sc = r * gamma[c];
    float sh = beta[c] - mean * sc;
    scsh[i] = make_float2(sc, sh);
}

__global__ __launch_bounds__(256) void norm_kernel(const float* __restrict__ x,
                                                   const int* __restrict__ ids,
                                                   const float2* __restrict__ scsh,
                                                   float* __restrict__ out, int HW) {
    // grid: (C, N)
    const int c = blockIdx.x;
    const int n = blockIdx.y;
    const int t = threadIdx.x;

    __shared__ float2 ls[K_INS];
    if (t < K_INS) ls[t] = scsh[((size_t)n * K_INS + t) * CCH + c];
    __syncthreads();

    const float4* xp = (const float4*)(x + ((size_t)n * CCH + c) * HW);
    const int4* ip = (const int4*)(ids + (size_t)n * HW);
    float4* op = (float4*)(out + ((size_t)n * CCH + c) * HW);

    const int iters = HW / (256 * 4);
    for (int j = 0; j < iters; ++j) {
        int idx = j * 256 + t;
        float4 xv = xp[idx];
        int4 id = ip[idx];
        float4 o;
        {
            float2 ss = ls[max(id.x, 0)];
            o.x = (id.x >= 0) ? fmaf(xv.x, ss.x, ss.y) : xv.x;
        }
        {
            float2 ss = ls[max(id.y, 0)];
            o.y = (id.y >= 0) ? fmaf(xv.y, ss.x, ss.y) : xv.y;
        }
        {
            float2 ss = ls[max(id.z, 0)];
            o.z = (id.z >= 0) ? fmaf(xv.z, ss.x, ss.y) : xv.z;
        }
        {
            float2 ss = ls[max(id.w, 0)];
            o.w = (id.w >= 0) ? fmaf(xv.w, ss.x, ss.y) : xv.w;
        }
        op[idx] = o;
    }
}

extern "C" void kernel_launch(void* const* d_in, const int* in_sizes, int n_in,
                              void* d_out, int out_size, void* d_ws, size_t ws_size,
                              hipStream_t stream) {
    const float* x = (const float*)d_in[0];
    const int* ids = (const int*)d_in[1];
    const float* gamma = (const float*)d_in[2];
    const float* beta = (const float*)d_in[3];
    float* out = (float*)d_out;

    const int HW = in_sizes[1] / N_IMG;  // 65536

    float2* stats = (float2*)((char*)d_ws + STATS_OFF);
    int* cnt = (int*)((char*)d_ws + CNT_OFF);
    float2* scsh = (float2*)((char*)d_ws + SCSH_OFF);

    // counts are accumulated with atomics -> must be zeroed every call
    hipMemsetAsync((char*)d_ws + CNT_OFF, 0, N_IMG * K_INS * sizeof(int), stream);

    count_kernel<<<dim3(32, N_IMG), 256, 0, stream>>>(ids, cnt, HW);
    stats_kernel<<<dim3(CCH, N_IMG), 256, 0, stream>>>(x, ids, stats, HW);
    finalize_kernel<<<dim3((N_IMG * K_INS * CCH + 255) / 256), 256, 0, stream>>>(
        stats, cnt, gamma, beta, scsh);
    norm_kernel<<<dim3(CCH, N_IMG), 256, 0, stream>>>(x, ids, scsh, out, HW);
}

// Round 3
// 151.228 us; speedup vs baseline: 2.8610x; 2.8610x over previous
//
#include <hip/hip_runtime.h>

#define N_IMG 8
#define K_INS 16
#define CCH   64
#define EPSV  1e-5f

// workspace layout (bytes):
//   [0, 65536)       float2 stats[N][K][C]  (sum, sumsq) -- fully written each call
//   [65536, 66048)   int    cnt[N][K]       -- zeroed via hipMemsetAsync each call
#define STATS_OFF 0
#define CNT_OFF   65536

__global__ __launch_bounds__(256) void count_kernel(const int* __restrict__ ids,
                                                    int* __restrict__ cnt, int HW) {
    // grid: (tilesPerImg=32, N). tile = HW/32 ids; each of 4 waves takes a quarter.
    const int n = blockIdx.y;
    const int tileSize = HW / 32;
    const int quarter = tileSize / 4;
    const int lane = threadIdx.x & 63;
    const int wave = threadIdx.x >> 6;
    const int wbase = blockIdx.x * tileSize + wave * quarter;
    const int* p = ids + (size_t)n * HW;

    int myc[K_INS];
#pragma unroll
    for (int k = 0; k < K_INS; ++k) myc[k] = 0;

    for (int i = wbase + lane; i < wbase + quarter; i += 64) {
        int id = p[i];
#pragma unroll
        for (int k = 0; k < K_INS; ++k) {
            unsigned long long m = __ballot(id == k);
            if (lane == 0) myc[k] += __popcll(m);
        }
    }
    if (lane == 0) {
#pragma unroll
        for (int k = 0; k < K_INS; ++k) atomicAdd(&cnt[n * K_INS + k], myc[k]);
    }
}

__global__ __launch_bounds__(256) void stats_kernel(const float* __restrict__ x,
                                                    const int* __restrict__ ids,
                                                    float2* __restrict__ stats, int HW) {
    // grid: (C, N). Block owns one (n,c).
    // Register-resident predicated accumulation: per element, 16x
    // {cmp, cndmask, add, fma} = 64 VALU lane-ops. No LDS RMW chains,
    // no runtime-indexed register arrays (all indices compile-time).
    const int c = blockIdx.x;
    const int n = blockIdx.y;
    const int t = threadIdx.x;

    float s[K_INS], q[K_INS];
#pragma unroll
    for (int k = 0; k < K_INS; ++k) { s[k] = 0.f; q[k] = 0.f; }

    const float4* x4 = (const float4*)(x + ((size_t)n * CCH + c) * HW);
    const int4* i4 = (const int4*)(ids + (size_t)n * HW);

    const int iters = HW / (256 * 4);  // 64
#pragma unroll 2
    for (int j = 0; j < iters; ++j) {
        int idx = j * 256 + t;
        float4 xv = x4[idx];
        int4 iv = i4[idx];
#pragma unroll
        for (int k = 0; k < K_INS; ++k) {
            float m0 = (iv.x == k) ? xv.x : 0.f;
            s[k] += m0;
            q[k] = fmaf(m0, xv.x, q[k]);
            float m1 = (iv.y == k) ? xv.y : 0.f;
            s[k] += m1;
            q[k] = fmaf(m1, xv.y, q[k]);
            float m2 = (iv.z == k) ? xv.z : 0.f;
            s[k] += m2;
            q[k] = fmaf(m2, xv.z, q[k]);
            float m3 = (iv.w == k) ? xv.w : 0.f;
            s[k] += m3;
            q[k] = fmaf(m3, xv.w, q[k]);
        }
    }

    // Block reduction: dump 16 float2 per thread to LDS, then 256 threads
    // reduce (k = t>>4, seg = t&15): each sums 16 partials (rotated index
    // to spread banks), then shfl-reduce across the 16-lane segment group.
    __shared__ float2 red[K_INS][256];
#pragma unroll
    for (int k = 0; k < K_INS; ++k) red[k][t] = make_float2(s[k], q[k]);
    __syncthreads();

    const int k = t >> 4;    // 0..15
    const int seg = t & 15;  // 0..15
    float rs = 0.f, rq = 0.f;
#pragma unroll
    for (int i = 0; i < 16; ++i) {
        float2 v = red[k][seg * 16 + ((i + seg) & 15)];
        rs += v.x;
        rq += v.y;
    }
#pragma unroll
    for (int off = 8; off > 0; off >>= 1) {
        rs += __shfl_down(rs, off, 16);
        rq += __shfl_down(rq, off, 16);
    }
    if (seg == 0) stats[((size_t)n * K_INS + k) * CCH + c] = make_float2(rs, rq);
}

__global__ __launch_bounds__(256) void norm_kernel(const float* __restrict__ x,
                                                   const int* __restrict__ ids,
                                                   const float2* __restrict__ stats,
                                                   const int* __restrict__ cnt,
                                                   const float* __restrict__ gamma,
                                                   const float* __restrict__ beta,
                                                   float* __restrict__ out, int HW) {
    // grid: (C, N). Finalize fused: first 16 threads build scale/shift in LDS.
    const int c = blockIdx.x;
    const int n = blockIdx.y;
    const int t = threadIdx.x;

    __shared__ float2 ls[K_INS];
    if (t < K_INS) {
        float2 sq = stats[((size_t)n * K_INS + t) * CCH + c];
        float denom = fmaxf((float)cnt[n * K_INS + t], 1.0f);
        float mean = sq.x / denom;
        float var = sq.y / denom - mean * mean;
        float r = rsqrtf(var + EPSV);
        float sc = r * gamma[c];
        float sh = beta[c] - mean * sc;
        ls[t] = make_float2(sc, sh);
    }
    __syncthreads();

    const float4* xp = (const float4*)(x + ((size_t)n * CCH + c) * HW);
    const int4* ip = (const int4*)(ids + (size_t)n * HW);
    float4* op = (float4*)(out + ((size_t)n * CCH + c) * HW);

    const int iters = HW / (256 * 4);
#pragma unroll 2
    for (int j = 0; j < iters; ++j) {
        int idx = j * 256 + t;
        float4 xv = xp[idx];
        int4 id = ip[idx];
        float4 o;
        {
            float2 ss = ls[max(id.x, 0)];
            o.x = (id.x >= 0) ? fmaf(xv.x, ss.x, ss.y) : xv.x;
        }
        {
            float2 ss = ls[max(id.y, 0)];
            o.y = (id.y >= 0) ? fmaf(xv.y, ss.x, ss.y) : xv.y;
        }
        {
            float2 ss = ls[max(id.z, 0)];
            o.z = (id.z >= 0) ? fmaf(xv.z, ss.x, ss.y) : xv.z;
        }
        {
            float2 ss = ls[max(id.w, 0)];
            o.w = (id.w >= 0) ? fmaf(xv.w, ss.x, ss.y) : xv.w;
        }
        op[idx] = o;
    }
}

extern "C" void kernel_launch(void* const* d_in, const int* in_sizes, int n_in,
                              void* d_out, int out_size, void* d_ws, size_t ws_size,
                              hipStream_t stream) {
    const float* x = (const float*)d_in[0];
    const int* ids = (const int*)d_in[1];
    const float* gamma = (const float*)d_in[2];
    const float* beta = (const float*)d_in[3];
    float* out = (float*)d_out;

    const int HW = in_sizes[1] / N_IMG;  // 65536

    float2* stats = (float2*)((char*)d_ws + STATS_OFF);
    int* cnt = (int*)((char*)d_ws + CNT_OFF);

    // counts are accumulated with atomics -> must be zeroed every call
    hipMemsetAsync((char*)d_ws + CNT_OFF, 0, N_IMG * K_INS * sizeof(int), stream);

    count_kernel<<<dim3(32, N_IMG), 256, 0, stream>>>(ids, cnt, HW);
    stats_kernel<<<dim3(CCH, N_IMG), 256, 0, stream>>>(x, ids, stats, HW);
    norm_kernel<<<dim3(CCH, N_IMG), 256, 0, stream>>>(x, ids, stats, cnt, gamma, beta, out, HW);
}